// Round 8
// baseline (361.371 us; speedup 1.0000x reference)
//
#include <hip/hip_runtime.h>

// YOLO head: input [B, 255, 80, 80] f32, anchors [3,2] f32
// output [B, 3*80*80, 85] f32.
// R7 evidence: kernel 127.8us, hbm 2.6TB/s (33%), VALUBusy 13%, LDS-conflict
// 3.7%, occupancy 45% -> latency/structure-bound, not BW/VALU/LDS-bound.
// R8: persistent software pipeline. 1024 fully-resident blocks (4/CU by LDS),
// each walks rows with stride 1024, prefetching next row's 7 float4 into
// registers while storing the current row -> continuous read+write overlap,
// no convoy, HBM latency hidden under store phase.

#define NA 3
#define ATTRS 85
#define GH 80
#define GW 80
#define HW 6400            // GH*GW
#define STRIDE_PX 8.0f     // 640/80

constexpr int TILE_ELEMS = ATTRS * GW;        // 6800 floats per row-tile
constexpr int TILE_F4    = TILE_ELEMS / 4;    // 1700
constexpr int NIT        = (TILE_F4 + 255) / 256;  // 7 quads/thread
constexpr int NBLK       = 1024;              // 4 blocks/CU x 256 CU, all resident

typedef float f32x4 __attribute__((ext_vector_type(4)));

// Fast sigmoid: v_exp_f32 + v_rcp_f32, rel err ~1e-7 (abs err <=1e-4 on px/py).
__device__ __forceinline__ float sigmoid_fast(float x) {
    float e = __builtin_amdgcn_exp2f(-x * 1.44269504088896341f);
    return __builtin_amdgcn_rcpf(1.0f + e);
}

__global__ __launch_bounds__(256, 4) void yolo_head_kernel(
    const float* __restrict__ in,
    const float* __restrict__ anchors,
    float* __restrict__ out,
    int nrows)
{
    __shared__ float tile[TILE_ELEMS];   // 27200 B, single buffer
    const int tid = threadIdx.x;

    int row = blockIdx.x;
    if (row >= nrows) return;

    // ---- prologue: prefetch first row into registers ----
    f32x4 cur[NIT];
    {
        const int ba = row / GH, h = row % GH;
        const float* src = in + (size_t)ba * (ATTRS * HW) + h * GW;
        #pragma unroll
        for (int it = 0; it < NIT; ++it) {
            const int li = tid + 256 * it;
            if (li < TILE_F4) {
                const int c = li / (GW / 4), v = li % (GW / 4);
                cur[it] = *reinterpret_cast<const f32x4*>(src + (size_t)c * HW + v * 4);
            }
        }
    }

    while (row < nrows) {
        const int ba = row / GH, h = row % GH, a = ba % NA;
        const float aw = anchors[2 * a + 0];
        const float ah = anchors[2 * a + 1];

        // ---- transform + output-linear LDS scatter of current row ----
        #pragma unroll
        for (int it = 0; it < NIT; ++it) {
            const int li = tid + 256 * it;
            if (li < TILE_F4) {
                const int c = li / (GW / 4), v = li % (GW / 4);
                #pragma unroll
                for (int j = 0; j < 4; ++j) {
                    const int w = v * 4 + j;
                    const float x = cur[it][j];
                    float r;
                    if (c == 0) {
                        r = (sigmoid_fast(x) + (float)w) * STRIDE_PX;
                    } else if (c == 1) {
                        r = (sigmoid_fast(x) + (float)h) * STRIDE_PX;
                    } else if (c == 2) {
                        // accurate expf: values up to exp(16)*40 ~ 3.5e8
                        r = expf(fminf(fmaxf(x, -16.0f), 16.0f)) * aw;
                    } else if (c == 3) {
                        r = expf(fminf(fmaxf(x, -16.0f), 16.0f)) * ah;
                    } else {
                        r = sigmoid_fast(x);
                    }
                    tile[w * ATTRS + c] = r;
                }
            }
        }

        const int nrow = row + NBLK;
        __syncthreads();

        // ---- issue next row's global loads (overlap with store phase) ----
        f32x4 nxt[NIT];
        if (nrow < nrows) {
            const int nba = nrow / GH, nh = nrow % GH;
            const float* src = in + (size_t)nba * (ATTRS * HW) + nh * GW;
            #pragma unroll
            for (int it = 0; it < NIT; ++it) {
                const int li = tid + 256 * it;
                if (li < TILE_F4) {
                    const int c = li / (GW / 4), v = li % (GW / 4);
                    nxt[it] = *reinterpret_cast<const f32x4*>(src + (size_t)c * HW + v * 4);
                }
            }
        }

        // ---- store current row: ds_read_b128 + coalesced NT writes ----
        f32x4* dst = reinterpret_cast<f32x4*>(out + (size_t)row * TILE_ELEMS);
        const f32x4* ts = reinterpret_cast<const f32x4*>(tile);
        #pragma unroll
        for (int it = 0; it < NIT; ++it) {
            const int oi = tid + 256 * it;
            if (oi < TILE_F4)
                __builtin_nontemporal_store(ts[oi], &dst[oi]);
        }

        __syncthreads();   // tile consumed; safe to overwrite next iteration

        #pragma unroll
        for (int it = 0; it < NIT; ++it) cur[it] = nxt[it];
        row = nrow;
    }
}

extern "C" void kernel_launch(void* const* d_in, const int* in_sizes, int n_in,
                              void* d_out, int out_size, void* d_ws, size_t ws_size,
                              hipStream_t stream) {
    const float* in      = (const float*)d_in[0];
    const float* anchors = (const float*)d_in[1];
    float* out           = (float*)d_out;

    const int B     = in_sizes[0] / (NA * ATTRS * HW);   // 32
    const int nrows = B * NA * GH;                        // 7680

    yolo_head_kernel<<<NBLK, 256, 0, stream>>>(in, anchors, out, nrows);
}